// Round 1
// baseline (520.756 us; speedup 1.0000x reference)
//
#include <hip/hip_runtime.h>

// BSplineBasis: T=262144 samples, K=512 cubic (DEGREE=3) basis functions,
// clamped knot vector of 516 fp32 knots. Only 4 bases are nonzero per sample;
// output is a dense (T, 512) fp32 array => 512 MiB, pure write-BW-bound.

namespace {
constexpr int K_N  = 512;    // final basis count (output columns)
constexpr int NKN  = 516;    // K + DEGREE + 1 knots
constexpr int DEG  = 3;
constexpr float EPSF = 1e-6f;
constexpr int ROWS = 16;     // rows (t samples) per block
constexpr int BLK  = 256;    // threads per block (4 waves)
}

__global__ __launch_bounds__(BLK)
void bspline_basis_kernel(const float* __restrict__ t_arr,
                          const float* __restrict__ knots,
                          float* __restrict__ out)
{
    __shared__ float kv[NKN];
    __shared__ float vals[ROWS][4];
    __shared__ int   j0s[ROWS];

    const int tid = threadIdx.x;
    // Stage knots in LDS (516 floats).
    for (int i = tid; i < NKN; i += BLK) kv[i] = knots[i];
    __syncthreads();

    const int row_base = blockIdx.x * ROWS;

    // Phase 1: threads 0..15 each compute the 4 nonzero basis values for one row.
    if (tid < ROWS) {
        const float t = t_arr[row_base + tid];
        int j0 = -16;                       // sentinel: all-zero row
        float N0 = 0.f, N1 = 0.f, N2 = 0.f, N3 = 0.f;
        // Reference semantics: degree-0 interval j=514 is [1,1] closed, but its
        // contribution dies at d=1 (kv[515]-kv[514]=0 < EPS), so t >= kv[512]
        // (i.e. t >= 1.0) yields an all-zero row. Replicate exactly.
        if (t < kv[K_N]) {
            // Largest s in [3, 511] with kv[s] <= t  =>  kv[s] <= t < kv[s+1],
            // identical fp32 comparisons to the reference's degree-0 test.
            int lo = DEG, hi = K_N - 1;
            while (lo < hi) {
                const int mid = (lo + hi + 1) >> 1;
                if (t >= kv[mid]) lo = mid; else hi = mid - 1;
            }
            const int s = lo;
            // Local Cox-de Boor: N[k] = B_{s-d+k, d}(t), k = 0..d.
            float N[4] = {1.f, 0.f, 0.f, 0.f};
            #pragma unroll
            for (int d = 1; d <= DEG; ++d) {
                float nn[4];
                #pragma unroll
                for (int k = 0; k <= d; ++k) {
                    const int j = s - d + k;
                    const float left  = (k >= 1)     ? N[k - 1] : 0.f;  // B_{j,d-1}
                    const float right = (k <= d - 1) ? N[k]     : 0.f;  // B_{j+1,d-1}
                    const float den1 = kv[j + d]     - kv[j];
                    const float den2 = kv[j + d + 1] - kv[j + 1];
                    // Reference: where(den >= EPS, num/den, 0)
                    const float c1 = (den1 >= EPSF) ? (t - kv[j]) / den1 : 0.f;
                    const float c2 = (den2 >= EPSF) ? (kv[j + d + 1] - t) / den2 : 0.f;
                    nn[k] = c1 * left + c2 * right;
                }
                #pragma unroll
                for (int k = 0; k <= d; ++k) N[k] = nn[k];
            }
            j0 = s - DEG;                   // first nonzero column, in [0, 508]
            N0 = N[0]; N1 = N[1]; N2 = N[2]; N3 = N[3];
        }
        j0s[tid] = j0;
        vals[tid][0] = N0; vals[tid][1] = N1;
        vals[tid][2] = N2; vals[tid][3] = N3;
    }
    __syncthreads();

    // Phase 2: dense coalesced write of 16 rows x 512 cols as float4.
    float4* out4 = reinterpret_cast<float4*>(out + (size_t)row_base * K_N);
    constexpr int TOTAL_F4 = ROWS * (K_N / 4);   // 2048 float4 per block
    #pragma unroll
    for (int it = 0; it < TOTAL_F4 / BLK; ++it) {
        const int idx = it * BLK + tid;          // consecutive lanes -> consecutive float4
        const int r   = idx >> 7;                // /128 float4 per row
        const int c   = (idx & 127) << 2;        // first column of this float4
        const int j0  = j0s[r];
        float e[4];
        #pragma unroll
        for (int k = 0; k < 4; ++k) {
            const int rel = c + k - j0;
            const float v = vals[r][rel & 3];    // always-safe LDS read
            e[k] = (rel >= 0 && rel <= 3) ? v : 0.f;
        }
        out4[idx] = make_float4(e[0], e[1], e[2], e[3]);
    }
}

extern "C" void kernel_launch(void* const* d_in, const int* in_sizes, int n_in,
                              void* d_out, int out_size, void* d_ws, size_t ws_size,
                              hipStream_t stream) {
    const float* t_arr = (const float*)d_in[0];
    const float* knots = (const float*)d_in[1];
    float* out = (float*)d_out;
    const int n_rows = in_sizes[0];              // 262144, divisible by ROWS
    dim3 grid(n_rows / ROWS);
    hipLaunchKernelGGL(bspline_basis_kernel, grid, dim3(BLK), 0, stream,
                       t_arr, knots, out);
}